// Round 11
// baseline (1031.555 us; speedup 1.0000x reference)
//
#include <hip/hip_runtime.h>

#define N_NODES 100000
#define N_EDGES 1600000
#define T_STEPS 6
#define FDIM    64
#define SEG     (T_STEPS * N_NODES)
#define C2      0.01f
#define NPW     4                       // nodes per wave in k_sum24

// Build per-(t,dst)-segment linked lists over edges. One atomicExch per edge
// on the 2.4MB head array (L2-resident).
__global__ __launch_bounds__(256) void k_build(
    const int* __restrict__ dst, const int* __restrict__ tix,
    int* __restrict__ head, int* __restrict__ nxt)
{
  const int e = blockIdx.x * blockDim.x + threadIdx.x;
  if (e >= N_EDGES) return;
  const int key = tix[e] * N_NODES + dst[e];
  nxt[e] = atomicExch(&head[key], e);
}

// One wave per 4 NODES, lane = feature: 24 independent chains interleaved
// (vs r9's 6) -> 4x memory-level parallelism on the latency-bound gather.
// Each (t,n) chain walks its list sequentially in the same order as r5-r9
// -> per-segment sums bit-identical.
__global__ __launch_bounds__(256) void k_sum24(
    const float* __restrict__ feat, const int* __restrict__ src,
    const int* __restrict__ head, const int* __restrict__ nxt,
    float* __restrict__ sums, float* __restrict__ cnt)
{
  const int lane = threadIdx.x & 63;
  const int w = blockIdx.x * (blockDim.x >> 6) + (threadIdx.x >> 6);
  const int n0 = w * NPW;
  if (n0 >= N_NODES) return;

  int e[T_STEPS * NPW];
  float v[T_STEPS * NPW];
  int c[T_STEPS * NPW];

  #pragma unroll
  for (int t = 0; t < T_STEPS; ++t)
    #pragma unroll
    for (int u = 0; u < NPW; ++u) {
      const int n = n0 + u;
      e[t * NPW + u] = (n < N_NODES) ? head[(size_t)t * N_NODES + n] : -1;
      v[t * NPW + u] = 0.0f;
      c[t * NPW + u] = 0;
    }

  bool any = true;
  while (any) {
    any = false;
    #pragma unroll
    for (int k = 0; k < T_STEPS * NPW; ++k) {
      if (e[k] >= 0) {
        v[k] += feat[(size_t)src[e[k]] * FDIM + lane];
        ++c[k];
        e[k] = nxt[e[k]];
        any = true;
      }
    }
  }

  #pragma unroll
  for (int t = 0; t < T_STEPS; ++t)
    #pragma unroll
    for (int u = 0; u < NPW; ++u) {
      const int n = n0 + u;
      if (n < N_NODES) {
        sums[((size_t)t * N_NODES + n) * FDIM + lane] = v[t * NPW + u];
        if (lane == 0) cnt[(size_t)t * N_NODES + n] = (float)c[t * NPW + u];
      }
    }
}

// Round-1 arithmetic (verbatim pass A + per-j pass B chains). One 256-thread
// block per 64-node group; the 4 waves are 4 j-slices of the SAME group:
//  - jb via readfirstlane -> SGPR -> compiler keeps W/bias loads scalar
//    (r7 lesson: raw threadIdx-derived jb made W loads divergent vectors).
//  - all slices on one CU -> sums rows read once from HBM, siblings hit
//    L1/L2 (r8-r10 lesson: cross-block slices refetched 3.6x = 554MB).
//  - 6252 waves = 24/CU (r6 lesson: 1563 waves was latency-bound).
template <int OUTF, int JBLK>
__global__ __launch_bounds__(256) void k_fused_gemm(
    const float* __restrict__ sums, const float* __restrict__ cnt,
    const float* __restrict__ W, const float* __restrict__ bias,
    float* __restrict__ out)
{
  const int lane = threadIdx.x & 63;
  const int jb = __builtin_amdgcn_readfirstlane((threadIdx.x >> 6) * JBLK);

  int n = blockIdx.x * 64 + lane;
  const bool valid = (n < N_NODES);
  if (!valid) n = N_NODES - 1;

  // ---- pass A: scale factors per t (verbatim round-1 arithmetic) ----
  float sc0, sc1, sc2, sc3, sc4, sc5;
  #pragma unroll
  for (int t = 0; t < T_STEPS; ++t) {
    const float c  = cnt[(size_t)t * N_NODES + n];
    const float rc = 1.0f / fmaxf(c, 1.0f);
    const float4* row = (const float4*)(sums + ((size_t)t * N_NODES + n) * FDIM);
    float ss = 0.0f;
    #pragma unroll
    for (int q = 0; q < FDIM / 4; ++q) {
      float4 v = row[q];
      float m0 = v.x * rc, m1 = v.y * rc, m2 = v.z * rc, m3 = v.w * rc;
      ss += m0 * m0 + m1 * m1 + m2 * m2 + m3 * m3;
    }
    const float norm = 1.0f - C2 * ss;
    const float s = rc / norm;
    if (t == 0) sc0 = s; else if (t == 1) sc1 = s; else if (t == 2) sc2 = s;
    else if (t == 3) sc3 = s; else if (t == 4) sc4 = s; else sc5 = s;
  }

  // ---- pass B: dense layer, j-slice [jb, jb+JBLK) ----
  float acc[JBLK];
  #pragma unroll
  for (int j = 0; j < JBLK; ++j) acc[j] = bias[jb + j];

  #pragma unroll 1
  for (int t = 0; t < T_STEPS; ++t) {
    const float s = (t == 0) ? sc0 : (t == 1) ? sc1 : (t == 2) ? sc2
                  : (t == 3) ? sc3 : (t == 4) ? sc4 : sc5;
    const float4* row = (const float4*)(sums + ((size_t)t * N_NODES + n) * FDIM);
    #pragma unroll
    for (int q8 = 0; q8 < FDIM / 8; ++q8) {
      const float4 a = row[q8 * 2 + 0];
      const float4 b4 = row[q8 * 2 + 1];
      const float hv[8] = {a.x, a.y, a.z, a.w, b4.x, b4.y, b4.z, b4.w};
      const float* wr = W + ((size_t)t * FDIM + q8 * 8) * OUTF + jb;
      #pragma unroll
      for (int i = 0; i < 8; ++i) {
        const float hs = hv[i] * s;
        #pragma unroll
        for (int j = 0; j < JBLK; ++j)
          acc[j] = fmaf(hs, wr[i * OUTF + j], acc[j]);
      }
    }
  }

  if (valid) {
    float* o = out + (size_t)n * OUTF + jb;
    #pragma unroll
    for (int j = 0; j < JBLK; ++j) o[j] = fmaxf(acc[j], 0.0f);
  }
}

extern "C" void kernel_launch(void* const* d_in, const int* in_sizes, int n_in,
                              void* d_out, int out_size, void* d_ws, size_t ws_size,
                              hipStream_t stream) {
  const float* x  = (const float*)d_in[0];
  const int*  ei  = (const int*)d_in[1];
  const int*  tix = (const int*)d_in[2];
  const float* W1 = (const float*)d_in[3];
  const float* b1 = (const float*)d_in[4];
  const float* W2 = (const float*)d_in[5];
  const float* b2 = (const float*)d_in[6];

  const int* src = ei;
  const int* dst = ei + N_EDGES;

  // Workspace: head[SEG] | nxt[NE] | sums[SEG*64] | cnt[SEG] | h1[NN*64]
  // head+nxt = 8.8MB (256B-multiple) -> sums rows 256B-aligned.
  int*   head = (int*)d_ws;
  int*   nxt  = head + SEG;
  float* sums = (float*)(nxt + N_EDGES);
  float* cnt  = sums + (size_t)SEG * FDIM;
  float* h1   = cnt + SEG;

  const int nwaves    = (N_NODES + NPW - 1) / NPW;          // 25000
  const int sum_grid  = (nwaves + 3) / 4;                   // 4 waves/block
  const int ngrp      = (N_NODES + 63) / 64;                // 1563 groups

  hipMemsetAsync(head, 0xFF, (size_t)SEG * sizeof(int), stream);
  k_build<<<(N_EDGES + 255) / 256, 256, 0, stream>>>(dst, tix, head, nxt);

  // Layer 1
  k_sum24<<<sum_grid, 256, 0, stream>>>(x, src, head, nxt, sums, cnt);
  k_fused_gemm<64, 16><<<ngrp, 256, 0, stream>>>(sums, cnt, W1, b1, h1);

  // Layer 2 (same edge lists; cnt identical but rewritten -- harmless)
  k_sum24<<<sum_grid, 256, 0, stream>>>(h1, src, head, nxt, sums, cnt);
  k_fused_gemm<16, 4><<<ngrp, 256, 0, stream>>>(sums, cnt, W2, b2, (float*)d_out);
}

// Round 12
// 854.481 us; speedup vs baseline: 1.2072x; 1.2072x over previous
//
#include <hip/hip_runtime.h>

#define N_NODES 100000
#define N_EDGES 1600000
#define T_STEPS 6
#define FDIM    64
#define SEG     (T_STEPS * N_NODES)
#define C2      0.01f
#define PADF    68   // padded LDS row: 68 floats = 17 quads; (17u+q)%8 spreads banks

// Build per-(t,dst)-segment linked lists over edges. One atomicExch per edge
// on the 2.4MB head array (L2-resident).
__global__ __launch_bounds__(256) void k_build(
    const int* __restrict__ dst, const int* __restrict__ tix,
    int* __restrict__ head, int* __restrict__ nxt)
{
  const int e = blockIdx.x * blockDim.x + threadIdx.x;
  if (e >= N_EDGES) return;
  const int key = tix[e] * N_NODES + dst[e];
  nxt[e] = atomicExch(&head[key], e);
}

// ===== VERBATIM r9 k_sum6 (195us, best measured scatter; r11's 24-chain
// variant regressed to 332us via VGPR/occupancy + straggler effects). =====
__global__ __launch_bounds__(256) void k_sum6(
    const float* __restrict__ feat, const int* __restrict__ src,
    const int* __restrict__ head, const int* __restrict__ nxt,
    float* __restrict__ sums, float* __restrict__ cnt)
{
  const int lane = threadIdx.x & 63;
  const int n = blockIdx.x * (blockDim.x >> 6) + (threadIdx.x >> 6);
  if (n >= N_NODES) return;

  int e0 = head[(size_t)0 * N_NODES + n];
  int e1 = head[(size_t)1 * N_NODES + n];
  int e2 = head[(size_t)2 * N_NODES + n];
  int e3 = head[(size_t)3 * N_NODES + n];
  int e4 = head[(size_t)4 * N_NODES + n];
  int e5 = head[(size_t)5 * N_NODES + n];

  float v0 = 0.f, v1 = 0.f, v2 = 0.f, v3 = 0.f, v4 = 0.f, v5 = 0.f;
  int c0 = 0, c1 = 0, c2 = 0, c3 = 0, c4 = 0, c5 = 0;

  while ((e0 >= 0) | (e1 >= 0) | (e2 >= 0) | (e3 >= 0) | (e4 >= 0) | (e5 >= 0)) {
    if (e0 >= 0) { v0 += feat[(size_t)src[e0] * FDIM + lane]; ++c0; e0 = nxt[e0]; }
    if (e1 >= 0) { v1 += feat[(size_t)src[e1] * FDIM + lane]; ++c1; e1 = nxt[e1]; }
    if (e2 >= 0) { v2 += feat[(size_t)src[e2] * FDIM + lane]; ++c2; e2 = nxt[e2]; }
    if (e3 >= 0) { v3 += feat[(size_t)src[e3] * FDIM + lane]; ++c3; e3 = nxt[e3]; }
    if (e4 >= 0) { v4 += feat[(size_t)src[e4] * FDIM + lane]; ++c4; e4 = nxt[e4]; }
    if (e5 >= 0) { v5 += feat[(size_t)src[e5] * FDIM + lane]; ++c5; e5 = nxt[e5]; }
  }

  sums[((size_t)0 * N_NODES + n) * FDIM + lane] = v0;
  sums[((size_t)1 * N_NODES + n) * FDIM + lane] = v1;
  sums[((size_t)2 * N_NODES + n) * FDIM + lane] = v2;
  sums[((size_t)3 * N_NODES + n) * FDIM + lane] = v3;
  sums[((size_t)4 * N_NODES + n) * FDIM + lane] = v4;
  sums[((size_t)5 * N_NODES + n) * FDIM + lane] = v5;
  if (lane == 0) {
    cnt[(size_t)0 * N_NODES + n] = (float)c0;
    cnt[(size_t)1 * N_NODES + n] = (float)c1;
    cnt[(size_t)2 * N_NODES + n] = (float)c2;
    cnt[(size_t)3 * N_NODES + n] = (float)c3;
    cnt[(size_t)4 * N_NODES + n] = (float)c4;
    cnt[(size_t)5 * N_NODES + n] = (float)c5;
  }
}

// LDS-staged gemm: one 256-thread block per 64-node group. Stage the group's
// 6x64 sums rows (96KB) into padded LDS ONCE (coalesced float4), then run the
// VERBATIM r1/r9 pass A + pass B against LDS. 4 waves = 4 j-slices:
//  - jb = readfirstlane(waveid)*JBLK -> SGPR -> W/bias loads stay scalar (r7).
//  - sums rows leave HBM exactly once (r8/r10: cross-block slices refetched
//    3.6x = 554MB; here FETCH ~= 152MB total).
//  - LDS pad 68: b128 quad-column = (u+q)%8 -> conflict-free minimum.
template <int OUTF, int JBLK>
__global__ __launch_bounds__(256) void k_gemm_lds(
    const float* __restrict__ sums, const float* __restrict__ cnt,
    const float* __restrict__ W, const float* __restrict__ bias,
    float* __restrict__ out)
{
  extern __shared__ float lds[];   // [6][64][PADF]
  const int tid = threadIdx.x;
  const int lane = tid & 63;
  const int n0 = blockIdx.x * 64;

  // ---- stage: 6*64 rows x 16 float4 = 6144 items, 24 per thread ----
  #pragma unroll
  for (int it = 0; it < 24; ++it) {
    const int item = tid + it * 256;
    const int q = item & 15;
    const int u = (item >> 4) & 63;
    const int t = item >> 10;
    const int n = n0 + u;
    float4 v = make_float4(0.f, 0.f, 0.f, 0.f);
    if (n < N_NODES)
      v = *(const float4*)(sums + ((size_t)t * N_NODES + n) * FDIM + q * 4);
    *(float4*)(lds + (size_t)(t * 64 + u) * PADF + q * 4) = v;
  }
  __syncthreads();

  const int jb = __builtin_amdgcn_readfirstlane(tid >> 6) * JBLK;

  int n = n0 + lane;
  const bool valid = (n < N_NODES);
  if (!valid) n = N_NODES - 1;

  // ---- pass A: scale factors per t (verbatim r1 arithmetic, rows in LDS) ----
  float sc0, sc1, sc2, sc3, sc4, sc5;
  #pragma unroll
  for (int t = 0; t < T_STEPS; ++t) {
    const float c  = cnt[(size_t)t * N_NODES + n];
    const float rc = 1.0f / fmaxf(c, 1.0f);
    const float4* row = (const float4*)(lds + (size_t)(t * 64 + lane) * PADF);
    float ss = 0.0f;
    #pragma unroll
    for (int q = 0; q < FDIM / 4; ++q) {
      float4 v = row[q];
      float m0 = v.x * rc, m1 = v.y * rc, m2 = v.z * rc, m3 = v.w * rc;
      ss += m0 * m0 + m1 * m1 + m2 * m2 + m3 * m3;
    }
    const float norm = 1.0f - C2 * ss;
    const float s = rc / norm;
    if (t == 0) sc0 = s; else if (t == 1) sc1 = s; else if (t == 2) sc2 = s;
    else if (t == 3) sc3 = s; else if (t == 4) sc4 = s; else sc5 = s;
  }

  // ---- pass B: dense layer, j-slice [jb, jb+JBLK), rows in LDS ----
  float acc[JBLK];
  #pragma unroll
  for (int j = 0; j < JBLK; ++j) acc[j] = bias[jb + j];

  #pragma unroll 1
  for (int t = 0; t < T_STEPS; ++t) {
    const float s = (t == 0) ? sc0 : (t == 1) ? sc1 : (t == 2) ? sc2
                  : (t == 3) ? sc3 : (t == 4) ? sc4 : sc5;
    const float4* row = (const float4*)(lds + (size_t)(t * 64 + lane) * PADF);
    #pragma unroll
    for (int q8 = 0; q8 < FDIM / 8; ++q8) {
      const float4 a = row[q8 * 2 + 0];
      const float4 b4 = row[q8 * 2 + 1];
      const float hv[8] = {a.x, a.y, a.z, a.w, b4.x, b4.y, b4.z, b4.w};
      const float* wr = W + ((size_t)t * FDIM + q8 * 8) * OUTF + jb;
      #pragma unroll
      for (int i = 0; i < 8; ++i) {
        const float hs = hv[i] * s;
        #pragma unroll
        for (int j = 0; j < JBLK; ++j)
          acc[j] = fmaf(hs, wr[i * OUTF + j], acc[j]);
      }
    }
  }

  if (valid) {
    float* o = out + (size_t)n * OUTF + jb;
    #pragma unroll
    for (int j = 0; j < JBLK; ++j) o[j] = fmaxf(acc[j], 0.0f);
  }
}

extern "C" void kernel_launch(void* const* d_in, const int* in_sizes, int n_in,
                              void* d_out, int out_size, void* d_ws, size_t ws_size,
                              hipStream_t stream) {
  const float* x  = (const float*)d_in[0];
  const int*  ei  = (const int*)d_in[1];
  const int*  tix = (const int*)d_in[2];
  const float* W1 = (const float*)d_in[3];
  const float* b1 = (const float*)d_in[4];
  const float* W2 = (const float*)d_in[5];
  const float* b2 = (const float*)d_in[6];

  const int* src = ei;
  const int* dst = ei + N_EDGES;

  // Workspace: head[SEG] | nxt[NE] | sums[SEG*64] | cnt[SEG] | h1[NN*64]
  // head+nxt = 8.8MB (256B-multiple) -> sums rows 256B-aligned.
  int*   head = (int*)d_ws;
  int*   nxt  = head + SEG;
  float* sums = (float*)(nxt + N_EDGES);
  float* cnt  = sums + (size_t)SEG * FDIM;
  float* h1   = cnt + SEG;

  const int sum_grid = (N_NODES + 3) / 4;        // k_sum6: 4 waves/block
  const int ngrp     = (N_NODES + 63) / 64;      // 1563 64-node groups
  constexpr unsigned LDSB = (unsigned)(T_STEPS * 64 * PADF * sizeof(float)); // 104448

  // >64KB dynamic LDS opt-in (gfx950 has 160KB/CU); harmless if no-op.
  (void)hipFuncSetAttribute((const void*)&k_gemm_lds<64, 16>,
                            hipFuncAttributeMaxDynamicSharedMemorySize, (int)LDSB);
  (void)hipFuncSetAttribute((const void*)&k_gemm_lds<16, 4>,
                            hipFuncAttributeMaxDynamicSharedMemorySize, (int)LDSB);

  hipMemsetAsync(head, 0xFF, (size_t)SEG * sizeof(int), stream);
  k_build<<<(N_EDGES + 255) / 256, 256, 0, stream>>>(dst, tix, head, nxt);

  // Layer 1
  k_sum6<<<sum_grid, 256, 0, stream>>>(x, src, head, nxt, sums, cnt);
  k_gemm_lds<64, 16><<<ngrp, 256, LDSB, stream>>>(sums, cnt, W1, b1, h1);

  // Layer 2 (same edge lists; cnt identical but rewritten -- harmless)
  k_sum6<<<sum_grid, 256, 0, stream>>>(h1, src, head, nxt, sums, cnt);
  k_gemm_lds<16, 4><<<ngrp, 256, LDSB, stream>>>(sums, cnt, W2, b2, (float*)d_out);
}

// Round 13
// 556.197 us; speedup vs baseline: 1.8547x; 1.5363x over previous
//
#include <hip/hip_runtime.h>

#define N_NODES 100000
#define N_EDGES 1600000
#define T_STEPS 6
#define FDIM    64
#define SEG     (T_STEPS * N_NODES)
#define C2      0.01f
#define PADF    68   // LDS row stride: 17 quads; (u+q)%8 -> minimum-aliasing b128

// Build per-(t,dst)-segment linked lists over edges. One atomicExch per edge
// on the 2.4MB head array (L2-resident).
__global__ __launch_bounds__(256) void k_build(
    const int* __restrict__ dst, const int* __restrict__ tix,
    int* __restrict__ head, int* __restrict__ nxt)
{
  const int e = blockIdx.x * blockDim.x + threadIdx.x;
  if (e >= N_EDGES) return;
  const int key = tix[e] * N_NODES + dst[e];
  nxt[e] = atomicExch(&head[key], e);
}

// One wave per NODE, lane = feature, 6 chains -- BRANCHLESS interleave.
// r9's guarded form serialized the 6 gathers (load->waitcnt->add->branch per
// chain: ~29k cy/wave, matching the measured 195us). Here all 6 {src,nxt,feat}
// loads are unconditional (index clamped to 0) and issue as one 18-load
// clause; results merged with cndmask. v += (e>=0 ? f : 0.0f) adds exactly
// 0.0f on dead chains -> per-segment sum chain bit-identical to r5-r12.
__global__ __launch_bounds__(256) void k_sum6(
    const float* __restrict__ feat, const int* __restrict__ src,
    const int* __restrict__ head, const int* __restrict__ nxt,
    float* __restrict__ sums, float* __restrict__ cnt)
{
  const int lane = threadIdx.x & 63;
  const int n = blockIdx.x * (blockDim.x >> 6) + (threadIdx.x >> 6);
  if (n >= N_NODES) return;

  int e0 = head[(size_t)0 * N_NODES + n];
  int e1 = head[(size_t)1 * N_NODES + n];
  int e2 = head[(size_t)2 * N_NODES + n];
  int e3 = head[(size_t)3 * N_NODES + n];
  int e4 = head[(size_t)4 * N_NODES + n];
  int e5 = head[(size_t)5 * N_NODES + n];

  float v0 = 0.f, v1 = 0.f, v2 = 0.f, v3 = 0.f, v4 = 0.f, v5 = 0.f;
  int c0 = 0, c1 = 0, c2 = 0, c3 = 0, c4 = 0, c5 = 0;

  while ((e0 >= 0) | (e1 >= 0) | (e2 >= 0) | (e3 >= 0) | (e4 >= 0) | (e5 >= 0)) {
    const int a0 = e0 < 0 ? 0 : e0, a1 = e1 < 0 ? 0 : e1, a2 = e2 < 0 ? 0 : e2;
    const int a3 = e3 < 0 ? 0 : e3, a4 = e4 < 0 ? 0 : e4, a5 = e5 < 0 ? 0 : e5;

    const int s0 = src[a0], s1 = src[a1], s2 = src[a2];
    const int s3 = src[a3], s4 = src[a4], s5 = src[a5];
    const int x0 = nxt[a0], x1 = nxt[a1], x2 = nxt[a2];
    const int x3 = nxt[a3], x4 = nxt[a4], x5 = nxt[a5];

    const float f0 = feat[(size_t)s0 * FDIM + lane];
    const float f1 = feat[(size_t)s1 * FDIM + lane];
    const float f2 = feat[(size_t)s2 * FDIM + lane];
    const float f3 = feat[(size_t)s3 * FDIM + lane];
    const float f4 = feat[(size_t)s4 * FDIM + lane];
    const float f5 = feat[(size_t)s5 * FDIM + lane];

    v0 += (e0 >= 0) ? f0 : 0.0f;  c0 += (e0 >= 0);  e0 = (e0 >= 0) ? x0 : -1;
    v1 += (e1 >= 0) ? f1 : 0.0f;  c1 += (e1 >= 0);  e1 = (e1 >= 0) ? x1 : -1;
    v2 += (e2 >= 0) ? f2 : 0.0f;  c2 += (e2 >= 0);  e2 = (e2 >= 0) ? x2 : -1;
    v3 += (e3 >= 0) ? f3 : 0.0f;  c3 += (e3 >= 0);  e3 = (e3 >= 0) ? x3 : -1;
    v4 += (e4 >= 0) ? f4 : 0.0f;  c4 += (e4 >= 0);  e4 = (e4 >= 0) ? x4 : -1;
    v5 += (e5 >= 0) ? f5 : 0.0f;  c5 += (e5 >= 0);  e5 = (e5 >= 0) ? x5 : -1;
  }

  sums[((size_t)0 * N_NODES + n) * FDIM + lane] = v0;
  sums[((size_t)1 * N_NODES + n) * FDIM + lane] = v1;
  sums[((size_t)2 * N_NODES + n) * FDIM + lane] = v2;
  sums[((size_t)3 * N_NODES + n) * FDIM + lane] = v3;
  sums[((size_t)4 * N_NODES + n) * FDIM + lane] = v4;
  sums[((size_t)5 * N_NODES + n) * FDIM + lane] = v5;
  if (lane == 0) {
    cnt[(size_t)0 * N_NODES + n] = (float)c0;
    cnt[(size_t)1 * N_NODES + n] = (float)c1;
    cnt[(size_t)2 * N_NODES + n] = (float)c2;
    cnt[(size_t)3 * N_NODES + n] = (float)c3;
    cnt[(size_t)4 * N_NODES + n] = (float)c4;
    cnt[(size_t)5 * N_NODES + n] = (float)c5;
  }
}

// LDS-staged gemm, PER-T tile (r12 post-mortem: 104KB all-t tile -> 1
// block/CU -> 10% occupancy; 17.4KB per-t tile -> ~8 blocks/CU). Pass A and
// pass B are fused into the t-loop: sc_t depends only on row t, and acc's
// t-ascending fma order is unchanged -> arithmetic verbatim r1/r12.
// 4 waves = 4 j-slices; jb via readfirstlane -> SGPR -> W loads stay scalar.
template <int OUTF, int JBLK>
__global__ __launch_bounds__(256) void k_gemm_tile(
    const float* __restrict__ sums, const float* __restrict__ cnt,
    const float* __restrict__ W, const float* __restrict__ bias,
    float* __restrict__ out)
{
  __shared__ float lds[64 * PADF];   // 17408 B, one t-slice
  const int tid = threadIdx.x;
  const int lane = tid & 63;
  const int n0 = blockIdx.x * 64;
  const int jb = __builtin_amdgcn_readfirstlane(tid >> 6) * JBLK;

  int n = n0 + lane;
  const bool valid = (n < N_NODES);
  if (!valid) n = N_NODES - 1;

  float acc[JBLK];
  #pragma unroll
  for (int j = 0; j < JBLK; ++j) acc[j] = bias[jb + j];

  #pragma unroll 1
  for (int t = 0; t < T_STEPS; ++t) {
    __syncthreads();   // previous tile fully consumed before overwrite
    // stage t-slice: 64 rows x 16 quads = 1024 items, 4 per thread, coalesced
    #pragma unroll
    for (int it = 0; it < 4; ++it) {
      const int item = tid + it * 256;
      const int q = item & 15;
      const int u = item >> 4;
      const int nn = n0 + u;
      float4 v = make_float4(0.f, 0.f, 0.f, 0.f);
      if (nn < N_NODES)
        v = *(const float4*)(sums + ((size_t)t * N_NODES + nn) * FDIM + q * 4);
      *(float4*)(lds + u * PADF + q * 4) = v;
    }
    __syncthreads();

    // ---- pass A for this t (verbatim r1 rounding) ----
    const float c  = cnt[(size_t)t * N_NODES + n];
    const float rc = 1.0f / fmaxf(c, 1.0f);
    const float4* row = (const float4*)(lds + lane * PADF);
    float ss = 0.0f;
    #pragma unroll
    for (int q = 0; q < FDIM / 4; ++q) {
      float4 v = row[q];
      float m0 = v.x * rc, m1 = v.y * rc, m2 = v.z * rc, m3 = v.w * rc;
      ss += m0 * m0 + m1 * m1 + m2 * m2 + m3 * m3;
    }
    const float norm = 1.0f - C2 * ss;
    const float s = rc / norm;

    // ---- pass B partial for this t, j-slice [jb, jb+JBLK) ----
    #pragma unroll
    for (int q8 = 0; q8 < FDIM / 8; ++q8) {
      const float4 a = row[q8 * 2 + 0];
      const float4 b4 = row[q8 * 2 + 1];
      const float hv[8] = {a.x, a.y, a.z, a.w, b4.x, b4.y, b4.z, b4.w};
      const float* wr = W + ((size_t)t * FDIM + q8 * 8) * OUTF + jb;
      #pragma unroll
      for (int i = 0; i < 8; ++i) {
        const float hs = hv[i] * s;
        #pragma unroll
        for (int j = 0; j < JBLK; ++j)
          acc[j] = fmaf(hs, wr[i * OUTF + j], acc[j]);
      }
    }
  }

  if (valid) {
    float* o = out + (size_t)n * OUTF + jb;
    #pragma unroll
    for (int j = 0; j < JBLK; ++j) o[j] = fmaxf(acc[j], 0.0f);
  }
}

extern "C" void kernel_launch(void* const* d_in, const int* in_sizes, int n_in,
                              void* d_out, int out_size, void* d_ws, size_t ws_size,
                              hipStream_t stream) {
  const float* x  = (const float*)d_in[0];
  const int*  ei  = (const int*)d_in[1];
  const int*  tix = (const int*)d_in[2];
  const float* W1 = (const float*)d_in[3];
  const float* b1 = (const float*)d_in[4];
  const float* W2 = (const float*)d_in[5];
  const float* b2 = (const float*)d_in[6];

  const int* src = ei;
  const int* dst = ei + N_EDGES;

  // Workspace: head[SEG] | nxt[NE] | sums[SEG*64] | cnt[SEG] | h1[NN*64]
  int*   head = (int*)d_ws;
  int*   nxt  = head + SEG;
  float* sums = (float*)(nxt + N_EDGES);
  float* cnt  = sums + (size_t)SEG * FDIM;
  float* h1   = cnt + SEG;

  const int sum_grid = (N_NODES + 3) / 4;        // k_sum6: 4 waves/block
  const int ngrp     = (N_NODES + 63) / 64;      // 1563 64-node groups

  hipMemsetAsync(head, 0xFF, (size_t)SEG * sizeof(int), stream);
  k_build<<<(N_EDGES + 255) / 256, 256, 0, stream>>>(dst, tix, head, nxt);

  // Layer 1
  k_sum6<<<sum_grid, 256, 0, stream>>>(x, src, head, nxt, sums, cnt);
  k_gemm_tile<64, 16><<<ngrp, 256, 0, stream>>>(sums, cnt, W1, b1, h1);

  // Layer 2 (same edge lists; cnt identical but rewritten -- harmless)
  k_sum6<<<sum_grid, 256, 0, stream>>>(h1, src, head, nxt, sums, cnt);
  k_gemm_tile<16, 4><<<ngrp, 256, 0, stream>>>(sums, cnt, W2, b2, (float*)d_out);
}